// Round 5
// baseline (303.628 us; speedup 1.0000x reference)
//
#include <hip/hip_runtime.h>
#include <math.h>

// Problem constants
static constexpr int NB  = 8;
static constexpr int NRC = 4096;
static constexpr int NKP = 20;
static constexpr int NF  = 256;
static constexpr int NHD = 4;
static constexpr int NKH = NKP * NHD;  // 80
static constexpr int KCL = 8;
static constexpr float SCALE = 0.0625f; // 1/sqrt(256)

// workspace layout (float offsets)
// WT [1024][256] at 0
// Mt [8][64 f4][8 cg][48] at 262144   (cg*10+cw cols; entry cw*4+fi = M[col][f4*4+fi])
// P  [8][80][4] at 458752  (zeroed each launch; atomicAdd from k3)
static constexpr int WT_OFF = 0;
static constexpr int MT_OFF = 262144;
static constexpr int MT_CNT = NB * 64 * 8 * 48;   // 196608
static constexpr int P_OFF  = MT_OFF + MT_CNT;    // 458752
static constexpr int P_CNT  = NB * NKH * 4;       // 2560

// K0: WT[c][f] = W[f][c]   (W is [256 f][1024 c]); 128 blocks, 32f x 64c tiles
__global__ __launch_bounds__(256) void k0_transpose(const float* __restrict__ W,
                                                    float* __restrict__ WT) {
    __shared__ float tile[32][65];
    int c0 = (blockIdx.x & 15) * 64;
    int f0 = (blockIdx.x >> 4) * 32;
    int lx = threadIdx.x & 63, ly = threadIdx.x >> 6;
#pragma unroll
    for (int rr = 0; rr < 8; ++rr) {
        int fr = ly + rr * 4;
        tile[fr][lx] = W[(f0 + fr) * 1024 + c0 + lx];
    }
    __syncthreads();
    int lf = threadIdx.x & 31, cy = threadIdx.x >> 5;
#pragma unroll
    for (int rr = 0; rr < 8; ++rr) {
        int cr = cy + rr * 8;
        WT[(c0 + cr) * 256 + f0 + lf] = tile[lf][cr];
    }
}

// K12: fused ft_dst + M for one (b, k, h-pair).  grid 320, 512 threads.
// phase1: ft[c] = sum_g h0[b,k,g] * W[g, hp*512 + c]           (coalesced)
// phase2: M[kh][f] = SCALE * sum_d WT[hp*512+hh*256+d][f]*ft[..] (coalesced)
__global__ __launch_bounds__(512) void k12_m(const float* __restrict__ h0,
                                             const float* __restrict__ W,
                                             const float* __restrict__ WT,
                                             float* __restrict__ Mt) {
    int bx = blockIdx.x;             // 320 = 8b * 20k * 2hp
    int b = bx / 40;
    int rem = bx % 40;
    int k = rem >> 1, hp = rem & 1;
    int tid = threadIdx.x;
    __shared__ float h0l[NF];
    __shared__ float ftl[512];
    if (tid < NF) h0l[tid] = h0[(b * NKP + k) * NF + tid];
    __syncthreads();
    {
        float a = 0.f;
        const float* wp = W + hp * 512 + tid;
#pragma unroll 4
        for (int g = 0; g < NF; ++g) a += h0l[g] * wp[g * 1024];
        ftl[tid] = a;
    }
    __syncthreads();
    {
        int f = tid & 255, hh = tid >> 8;
        int h = hp * 2 + hh;
        int kh = k * NHD + h;
        float a = 0.f;
        const float* wtp = WT + (hp * 512 + hh * 256) * 256 + f;
        const float* fp = ftl + hh * 256;
#pragma unroll 4
        for (int d = 0; d < 256; ++d) a += fp[d] * wtp[d * 256];
        int cg = kh / 10, cw = kh % 10;
        Mt[(size_t)b * 24576 + (f >> 2) * 384 + cg * 48 + cw * 4 + (f & 3)] = a * SCALE;
    }
}

// K3: scores + exp + weighted sums, atomically accumulated into P[b][kh][4].
// grid 512 = (b, 64-row tile); 512 threads = 8 waves.
// r = lane owns one row; wave cg owns 10 cols. A staged in LDS transposed+
// swizzled [32 f4][64 r] per 128-f pass (32 KB); M reads full-wave-uniform.
__global__ __launch_bounds__(512) void k3_scores(const float* __restrict__ hrec,
                                                 const float* __restrict__ xrec,
                                                 const float* __restrict__ Mt,
                                                 float* __restrict__ P) {
    __shared__ float4 ldsA[2048];   // 32 KB
    int bx = blockIdx.x;
    int b = bx >> 6, t = bx & 63;
    int tid = threadIdx.x;
    int r = tid & 63, cg = tid >> 6;
    int rowbase = t * 64;

    float acc[10];
#pragma unroll
    for (int c = 0; c < 10; ++c) acc[c] = 0.f;

    const float* Mb = Mt + (size_t)b * 24576 + cg * 48;

    for (int pass = 0; pass < 2; ++pass) {
        if (pass) __syncthreads();
#pragma unroll
        for (int j = 0; j < 4; ++j) {
            int c = j * 512 + tid;
            int row = c >> 5, fc = c & 31;
            const float4* src = (const float4*)(hrec +
                ((size_t)(b * NRC + rowbase + row)) * NF + pass * 128 + fc * 4);
            ldsA[fc * 64 + (row ^ (fc & 7))] = *src;
        }
        __syncthreads();
#pragma unroll 2
        for (int fc = 0; fc < 32; ++fc) {
            float4 a = ldsA[fc * 64 + (r ^ (fc & 7))];
            const float* mp = Mb + (pass * 32 + fc) * 384;
#pragma unroll
            for (int c = 0; c < 10; ++c) {
                float4 m = *(const float4*)(mp + c * 4);
                acc[c] += a.x * m.x + a.y * m.y + a.z * m.z + a.w * m.w;
            }
        }
    }

    const float* xr = xrec + ((size_t)(b * NRC + rowbase + r)) * 3;
    float xx = xr[0], xy = xr[1], xz = xr[2];

    float* Pb = P + (b * NKH + cg * 10) * 4;
#pragma unroll
    for (int c = 0; c < 10; ++c) {
        float e = __expf(acc[c]);
        float s0 = e, s1 = e * xx, s2 = e * xy, s3 = e * xz;
#pragma unroll
        for (int m = 1; m < 64; m <<= 1) {
            s0 += __shfl_xor(s0, m, 64);
            s1 += __shfl_xor(s1, m, 64);
            s2 += __shfl_xor(s2, m, 64);
            s3 += __shfl_xor(s3, m, 64);
        }
        if (r == 0) {
            atomicAdd(&Pb[c * 4 + 0], s0);
            atomicAdd(&Pb[c * 4 + 1], s1);
            atomicAdd(&Pb[c * 4 + 2], s2);
            atomicAdd(&Pb[c * 4 + 3], s3);
        }
    }
}

#define CSWAP(i, j)                                                         \
    if (d[j] < d[i] || (d[j] == d[i] && ix[j] < ix[i])) {                   \
        float td = d[i]; d[i] = d[j]; d[j] = td;                            \
        int ti = ix[i]; ix[i] = ix[j]; ix[j] = ti;                          \
    }

// K4: per (b,k): kp_pos from P, top-8 via sorted register queues, knn mean,
// MLP+SiLU, LN.  grid 160 blocks, 512 threads.
__global__ __launch_bounds__(512) void k4_final(const float* __restrict__ hrec,
                                                const float* __restrict__ xrec,
                                                const float* __restrict__ P,
                                                const float* __restrict__ Wm,
                                                const float* __restrict__ bm,
                                                const float* __restrict__ gam,
                                                const float* __restrict__ bet,
                                                float* __restrict__ out) {
    int bx = blockIdx.x;
    int b = bx / NKP, k = bx % NKP;
    int tid = threadIdx.x;
    int w = tid >> 6, lane = tid & 63;

    __shared__ float Sh[16];
    __shared__ float posl[4];
    __shared__ float redv[8];
    __shared__ int   redi[8];
    __shared__ int   kidxs[KCL];
    __shared__ float fin[NF + KCL];
    __shared__ float part[2][NF];
    __shared__ float wred[8][2];
    __shared__ float stat[2];

    // phase 0: kp_pos directly from pre-summed P
    if (tid < 16)
        Sh[tid] = P[(b * NKH + k * NHD + (tid >> 2)) * 4 + (tid & 3)];
    __syncthreads();
    if (tid == 0) {
#pragma unroll
        for (int c = 0; c < 3; ++c) {
            float p = 0.f;
#pragma unroll
            for (int h = 0; h < NHD; ++h) p += Sh[h * 4 + c + 1] / Sh[h * 4];
            p *= 0.25f;
            posl[c] = p;
            out[(b * NKP + k) * 3 + c] = p;
        }
    }
    __syncthreads();

    // phase 1: d2 for 8 atoms/thread in registers, sorted
    float px = posl[0], py = posl[1], pz = posl[2];
    float d[8];
    int ix[8];
#pragma unroll
    for (int s = 0; s < 8; ++s) {
        int i = s * 512 + tid;
        const float* x = xrec + ((size_t)b * NRC + i) * 3;
        float dx = x[0] - px, dy = x[1] - py, dz = x[2] - pz;
        d[s] = dx * dx + dy * dy + dz * dz;
        ix[s] = i;
    }
    CSWAP(0, 1) CSWAP(2, 3) CSWAP(4, 5) CSWAP(6, 7)
    CSWAP(0, 2) CSWAP(1, 3) CSWAP(4, 6) CSWAP(5, 7)
    CSWAP(1, 2) CSWAP(5, 6)
    CSWAP(0, 4) CSWAP(1, 5) CSWAP(2, 6) CSWAP(3, 7)
    CSWAP(2, 4) CSWAP(3, 5)
    CSWAP(1, 2) CSWAP(3, 4) CSWAP(5, 6)

    // phase 2: 8 extraction rounds
    for (int j = 0; j < KCL; ++j) {
        float bd = d[0];
        int bi = ix[0];
#pragma unroll
        for (int m = 1; m < 64; m <<= 1) {
            float od = __shfl_xor(bd, m, 64);
            int oi = __shfl_xor(bi, m, 64);
            if (od < bd || (od == bd && oi < bi)) { bd = od; bi = oi; }
        }
        if (lane == 0) { redv[w] = bd; redi[w] = bi; }
        __syncthreads();
        bd = redv[0]; bi = redi[0];
#pragma unroll
        for (int q = 1; q < 8; ++q) {
            float od = redv[q]; int oi = redi[q];
            if (od < bd || (od == bd && oi < bi)) { bd = od; bi = oi; }
        }
        if (tid == 0) { kidxs[j] = bi; fin[NF + j] = sqrtf(bd); }
        if (ix[0] == bi) {
#pragma unroll
            for (int s = 0; s < 7; ++s) { d[s] = d[s + 1]; ix[s] = ix[s + 1]; }
            d[7] = 3.4e38f; ix[7] = 0x7fffffff;
        }
        __syncthreads();
    }

    // phase 3: knn feature mean
    if (tid < NF) {
        float hm = 0.f;
#pragma unroll
        for (int j = 0; j < KCL; ++j)
            hm += hrec[((size_t)b * NRC + kidxs[j]) * NF + tid];
        fin[tid] = hm * 0.125f;
    }
    __syncthreads();

    // phase 4: MLP 264 -> 256, split 2 ways over input dim
    {
        int o = tid & 255, p = tid >> 8;
        float acc = 0.f;
        const float* wp = Wm + o;
#pragma unroll 2
        for (int i = p * 132; i < p * 132 + 132; ++i)
            acc += fin[i] * wp[i * NF];
        part[p][o] = acc;
    }
    __syncthreads();

    float v = 0.f;
    if (tid < NF) {
        float psum = bm[tid] + part[0][tid] + part[1][tid];
        v = psum / (1.f + __expf(-psum));
    }
    // phase 5: LayerNorm
    float s = v, sq = v * v;
#pragma unroll
    for (int m = 1; m < 64; m <<= 1) {
        s += __shfl_xor(s, m, 64);
        sq += __shfl_xor(sq, m, 64);
    }
    if (lane == 0) { wred[w][0] = s; wred[w][1] = sq; }
    __syncthreads();
    if (tid == 0) {
        float ts = 0.f, tq = 0.f;
#pragma unroll
        for (int q = 0; q < 8; ++q) { ts += wred[q][0]; tq += wred[q][1]; }
        float mu = ts / 256.f;
        float var = tq / 256.f - mu * mu;
        stat[0] = mu;
        stat[1] = rsqrtf(var + 1e-5f);
    }
    __syncthreads();
    if (tid < NF) {
        float o = (v - stat[0]) * stat[1] * gam[tid] + bet[tid];
        out[NB * NKP * 3 + (b * NKP + k) * NF + tid] = o;
    }
}

extern "C" void kernel_launch(void* const* d_in, const int* in_sizes, int n_in,
                              void* d_out, int out_size, void* d_ws, size_t ws_size,
                              hipStream_t stream) {
    const float* h_rec = (const float*)d_in[0];
    const float* x_rec = (const float*)d_in[1];
    const float* h0_kp = (const float*)d_in[2];
    const float* W_src = (const float*)d_in[3];
    const float* W_mlp = (const float*)d_in[4];
    const float* b_mlp = (const float*)d_in[5];
    const float* gam   = (const float*)d_in[6];
    const float* bet   = (const float*)d_in[7];
    float* outp = (float*)d_out;
    float* ws = (float*)d_ws;

    float* WT = ws + WT_OFF;
    float* Mt = ws + MT_OFF;
    float* P  = ws + P_OFF;

    hipMemsetAsync(P, 0, P_CNT * sizeof(float), stream);
    hipLaunchKernelGGL(k0_transpose, dim3(128), dim3(256), 0, stream, W_src, WT);
    hipLaunchKernelGGL(k12_m, dim3(320), dim3(512), 0, stream, h0_kp, W_src, WT, Mt);
    hipLaunchKernelGGL(k3_scores, dim3(512), dim3(512), 0, stream,
                       h_rec, x_rec, Mt, P);
    hipLaunchKernelGGL(k4_final, dim3(160), dim3(512), 0, stream,
                       h_rec, x_rec, P, W_mlp, b_mlp, gam, bet, outp);
}

// Round 7
// 250.040 us; speedup vs baseline: 1.2143x; 1.2143x over previous
//
#include <hip/hip_runtime.h>
#include <math.h>

// Problem constants
static constexpr int NB  = 8;
static constexpr int NRC = 4096;
static constexpr int NKP = 20;
static constexpr int NF  = 256;
static constexpr int NHD = 4;
static constexpr int NKH = NKP * NHD;  // 80
static constexpr int KCL = 8;
static constexpr float SCALE = 0.0625f; // 1/sqrt(256)

// workspace layout (float offsets)
// WT [1024][256] at 0
// M  [8][80][256] at 262144
// P  [8][80][4] at 425984  (zeroed by k0; atomicAdd from k3)
static constexpr int WT_OFF = 0;
static constexpr int M_OFF  = 262144;
static constexpr int M_CNT  = NB * NKH * NF;      // 163840
static constexpr int P_OFF  = M_OFF + M_CNT;      // 425984
static constexpr int P_CNT  = NB * NKH * 4;       // 2560

// K0: WT[c][f] = W[f][c]  (W is [256 f][1024 c]); also zeroes P.
__global__ __launch_bounds__(256) void k0_transpose(const float* __restrict__ W,
                                                    float* __restrict__ WT,
                                                    float* __restrict__ P) {
    __shared__ float tile[32][65];
    if (blockIdx.x == 0) {
        for (int i = threadIdx.x; i < P_CNT; i += 256) P[i] = 0.f;
    }
    int c0 = (blockIdx.x & 15) * 64;
    int f0 = (blockIdx.x >> 4) * 32;
    int lx = threadIdx.x & 63, ly = threadIdx.x >> 6;
#pragma unroll
    for (int rr = 0; rr < 8; ++rr) {
        int fr = ly + rr * 4;
        tile[fr][lx] = W[(f0 + fr) * 1024 + c0 + lx];
    }
    __syncthreads();
    int lf = threadIdx.x & 31, cy = threadIdx.x >> 5;
#pragma unroll
    for (int rr = 0; rr < 8; ++rr) {
        int cr = cy + rr * 8;
        WT[(c0 + cr) * 256 + f0 + lf] = tile[lf][cr];
    }
}

// K12: fused ft_dst + M for one (b, k, h-pair).  grid 320, 512 threads.
__global__ __launch_bounds__(512) void k12_m(const float* __restrict__ h0,
                                             const float* __restrict__ W,
                                             const float* __restrict__ WT,
                                             float* __restrict__ M) {
    int bx = blockIdx.x;             // 320 = 8b * 20k * 2hp
    int b = bx / 40;
    int rem = bx % 40;
    int k = rem >> 1, hp = rem & 1;
    int tid = threadIdx.x;
    __shared__ float h0l[NF];
    __shared__ float ftl[512];
    if (tid < NF) h0l[tid] = h0[(b * NKP + k) * NF + tid];
    __syncthreads();
    {
        float a = 0.f;
        const float* wp = W + hp * 512 + tid;
#pragma unroll 8
        for (int g = 0; g < NF; ++g) a += h0l[g] * wp[g * 1024];
        ftl[tid] = a;
    }
    __syncthreads();
    {
        int f = tid & 255, hh = tid >> 8;
        int kh = k * NHD + hp * 2 + hh;
        float a = 0.f;
        const float* wtp = WT + (hp * 512 + hh * 256) * 256 + f;
        const float* fp = ftl + hh * 256;
#pragma unroll 8
        for (int d = 0; d < 256; ++d) a += fp[d] * wtp[d * 256];
        M[((size_t)b * NKH + kh) * NF + f] = a * SCALE;
    }
}

// K3: scores + exp + weighted sums, atomicAdd into P[b][kh][4].
// grid 1024 = (b, 32-row tile); 512 threads = 8 waves.
// Both A-tile and M-half staged in LDS (57.9 KB): per f-pass of 128,
// ldsA [32 fc][33 rows] (padded: conflict-free write+read),
// ldsM [80 col][32 fc] (write coalesced; compute read = 2-addr broadcast).
// Thread = (row r = tid&31, col-group colg = tid>>5 owning 5 cols).
__global__ __launch_bounds__(512) void k3_scores(const float* __restrict__ hrec,
                                                 const float* __restrict__ xrec,
                                                 const float* __restrict__ Mg,
                                                 float* __restrict__ P) {
    __shared__ float4 ldsA[32 * 33];   // 16.9 KB
    __shared__ float4 ldsM[80 * 32];   // 40 KB
    int bx = blockIdx.x;
    int b = bx >> 7, t = bx & 127;
    int tid = threadIdx.x;
    int r = tid & 31, colg = tid >> 5;
    int rowbase = t * 32;

    float acc[5] = {0.f, 0.f, 0.f, 0.f, 0.f};

    for (int pass = 0; pass < 2; ++pass) {
        if (pass) __syncthreads();
        // stage A-tile: 32 rows x 32 f4 (1024 float4s, 2/thread, coalesced)
#pragma unroll
        for (int j = 0; j < 2; ++j) {
            int c = j * 512 + tid;
            int row = c >> 5, fc = c & 31;
            ldsA[fc * 33 + row] = *(const float4*)(hrec +
                ((size_t)(b * NRC + rowbase + row)) * NF + pass * 128 + fc * 4);
        }
        // stage M-half: 80 cols x 32 f4 (2560 float4s, 5/thread, coalesced)
#pragma unroll
        for (int j = 0; j < 5; ++j) {
            int c = j * 512 + tid;
            int col = c >> 5, fc = c & 31;
            ldsM[col * 32 + fc] = *(const float4*)(Mg +
                ((size_t)b * NKH + col) * NF + pass * 128 + fc * 4);
        }
        __syncthreads();
#pragma unroll 4
        for (int fc = 0; fc < 32; ++fc) {
            float4 a = ldsA[fc * 33 + r];
            const float4* mp = ldsM + (colg * 5) * 32 + fc;
#pragma unroll
            for (int c = 0; c < 5; ++c) {
                float4 m = mp[c * 32];
                acc[c] += a.x * m.x + a.y * m.y + a.z * m.z + a.w * m.w;
            }
        }
    }

    const float* xr = xrec + ((size_t)(b * NRC + rowbase + r)) * 3;
    float xx = xr[0], xy = xr[1], xz = xr[2];

    float* Pb = P + ((size_t)b * NKH + colg * 5) * 4;
#pragma unroll
    for (int c = 0; c < 5; ++c) {
        float e = __expf(acc[c]);
        float s0 = e, s1 = e * xx, s2 = e * xy, s3 = e * xz;
#pragma unroll
        for (int m = 1; m < 32; m <<= 1) {   // reduce within 32-lane row group
            s0 += __shfl_xor(s0, m, 64);
            s1 += __shfl_xor(s1, m, 64);
            s2 += __shfl_xor(s2, m, 64);
            s3 += __shfl_xor(s3, m, 64);
        }
        if (r == 0) {
            atomicAdd(&Pb[c * 4 + 0], s0);
            atomicAdd(&Pb[c * 4 + 1], s1);
            atomicAdd(&Pb[c * 4 + 2], s2);
            atomicAdd(&Pb[c * 4 + 3], s3);
        }
    }
}

#define CSWAP(i, j)                                                         \
    if (d[j] < d[i] || (d[j] == d[i] && ix[j] < ix[i])) {                   \
        float td = d[i]; d[i] = d[j]; d[j] = td;                            \
        int ti = ix[i]; ix[i] = ix[j]; ix[j] = ti;                          \
    }

// K4: per (b,k): kp_pos from P, top-8 via sorted register queues, knn mean,
// MLP+SiLU, LN.  grid 160 blocks, 512 threads.
__global__ __launch_bounds__(512) void k4_final(const float* __restrict__ hrec,
                                                const float* __restrict__ xrec,
                                                const float* __restrict__ P,
                                                const float* __restrict__ Wm,
                                                const float* __restrict__ bm,
                                                const float* __restrict__ gam,
                                                const float* __restrict__ bet,
                                                float* __restrict__ out) {
    int bx = blockIdx.x;
    int b = bx / NKP, k = bx % NKP;
    int tid = threadIdx.x;
    int w = tid >> 6, lane = tid & 63;

    __shared__ float Sh[16];
    __shared__ float posl[4];
    __shared__ float redv[8];
    __shared__ int   redi[8];
    __shared__ int   kidxs[KCL];
    __shared__ float fin[NF + KCL];
    __shared__ float part[2][NF];
    __shared__ float wred[8][2];
    __shared__ float stat[2];

    // phase 0: kp_pos directly from pre-summed P
    if (tid < 16)
        Sh[tid] = P[(b * NKH + k * NHD + (tid >> 2)) * 4 + (tid & 3)];
    __syncthreads();
    if (tid == 0) {
#pragma unroll
        for (int c = 0; c < 3; ++c) {
            float p = 0.f;
#pragma unroll
            for (int h = 0; h < NHD; ++h) p += Sh[h * 4 + c + 1] / Sh[h * 4];
            p *= 0.25f;
            posl[c] = p;
            out[(b * NKP + k) * 3 + c] = p;
        }
    }
    __syncthreads();

    // phase 1: d2 for 8 atoms/thread in registers, sorted
    float px = posl[0], py = posl[1], pz = posl[2];
    float d[8];
    int ix[8];
#pragma unroll
    for (int s = 0; s < 8; ++s) {
        int i = s * 512 + tid;
        const float* x = xrec + ((size_t)b * NRC + i) * 3;
        float dx = x[0] - px, dy = x[1] - py, dz = x[2] - pz;
        d[s] = dx * dx + dy * dy + dz * dz;
        ix[s] = i;
    }
    CSWAP(0, 1) CSWAP(2, 3) CSWAP(4, 5) CSWAP(6, 7)
    CSWAP(0, 2) CSWAP(1, 3) CSWAP(4, 6) CSWAP(5, 7)
    CSWAP(1, 2) CSWAP(5, 6)
    CSWAP(0, 4) CSWAP(1, 5) CSWAP(2, 6) CSWAP(3, 7)
    CSWAP(2, 4) CSWAP(3, 5)
    CSWAP(1, 2) CSWAP(3, 4) CSWAP(5, 6)

    // phase 2: 8 extraction rounds
    for (int j = 0; j < KCL; ++j) {
        float bd = d[0];
        int bi = ix[0];
#pragma unroll
        for (int m = 1; m < 64; m <<= 1) {
            float od = __shfl_xor(bd, m, 64);
            int oi = __shfl_xor(bi, m, 64);
            if (od < bd || (od == bd && oi < bi)) { bd = od; bi = oi; }
        }
        if (lane == 0) { redv[w] = bd; redi[w] = bi; }
        __syncthreads();
        bd = redv[0]; bi = redi[0];
#pragma unroll
        for (int q = 1; q < 8; ++q) {
            float od = redv[q]; int oi = redi[q];
            if (od < bd || (od == bd && oi < bi)) { bd = od; bi = oi; }
        }
        if (tid == 0) { kidxs[j] = bi; fin[NF + j] = sqrtf(bd); }
        if (ix[0] == bi) {
#pragma unroll
            for (int s = 0; s < 7; ++s) { d[s] = d[s + 1]; ix[s] = ix[s + 1]; }
            d[7] = 3.4e38f; ix[7] = 0x7fffffff;
        }
        __syncthreads();
    }

    // phase 3: knn feature mean
    if (tid < NF) {
        float hm = 0.f;
#pragma unroll
        for (int j = 0; j < KCL; ++j)
            hm += hrec[((size_t)b * NRC + kidxs[j]) * NF + tid];
        fin[tid] = hm * 0.125f;
    }
    __syncthreads();

    // phase 4: MLP 264 -> 256, split 2 ways over input dim
    {
        int o = tid & 255, p = tid >> 8;
        float acc = 0.f;
        const float* wp = Wm + o;
#pragma unroll 8
        for (int i = p * 132; i < p * 132 + 132; ++i)
            acc += fin[i] * wp[i * NF];
        part[p][o] = acc;
    }
    __syncthreads();

    float v = 0.f;
    if (tid < NF) {
        float psum = bm[tid] + part[0][tid] + part[1][tid];
        v = psum / (1.f + __expf(-psum));
    }
    // phase 5: LayerNorm
    float s = v, sq = v * v;
#pragma unroll
    for (int m = 1; m < 64; m <<= 1) {
        s += __shfl_xor(s, m, 64);
        sq += __shfl_xor(sq, m, 64);
    }
    if (lane == 0) { wred[w][0] = s; wred[w][1] = sq; }
    __syncthreads();
    if (tid == 0) {
        float ts = 0.f, tq = 0.f;
#pragma unroll
        for (int q = 0; q < 8; ++q) { ts += wred[q][0]; tq += wred[q][1]; }
        float mu = ts / 256.f;
        float var = tq / 256.f - mu * mu;
        stat[0] = mu;
        stat[1] = rsqrtf(var + 1e-5f);
    }
    __syncthreads();
    if (tid < NF) {
        float o = (v - stat[0]) * stat[1] * gam[tid] + bet[tid];
        out[NB * NKP * 3 + (b * NKP + k) * NF + tid] = o;
    }
}

extern "C" void kernel_launch(void* const* d_in, const int* in_sizes, int n_in,
                              void* d_out, int out_size, void* d_ws, size_t ws_size,
                              hipStream_t stream) {
    const float* h_rec = (const float*)d_in[0];
    const float* x_rec = (const float*)d_in[1];
    const float* h0_kp = (const float*)d_in[2];
    const float* W_src = (const float*)d_in[3];
    const float* W_mlp = (const float*)d_in[4];
    const float* b_mlp = (const float*)d_in[5];
    const float* gam   = (const float*)d_in[6];
    const float* bet   = (const float*)d_in[7];
    float* outp = (float*)d_out;
    float* ws = (float*)d_ws;

    float* WT = ws + WT_OFF;
    float* M  = ws + M_OFF;
    float* P  = ws + P_OFF;

    hipLaunchKernelGGL(k0_transpose, dim3(128), dim3(256), 0, stream, W_src, WT, P);
    hipLaunchKernelGGL(k12_m, dim3(320), dim3(512), 0, stream, h0_kp, W_src, WT, M);
    hipLaunchKernelGGL(k3_scores, dim3(1024), dim3(512), 0, stream,
                       h_rec, x_rec, M, P);
    hipLaunchKernelGGL(k4_final, dim3(160), dim3(512), 0, stream,
                       h_rec, x_rec, P, W_mlp, b_mlp, gam, bet, outp);
}